// Round 5
// baseline (161.950 us; speedup 1.0000x reference)
//
#include <hip/hip_runtime.h>
#include <stdint.h>

#define S      56
#define NC     20
#define NCELL  3136
#define NBOXES 6272
#define DIM    94080
#define BD1    62720          // NCELL*NC
#define BD2    68992          // BD1 + NCELL*2
#define CAND   256
#define MAXOUT 30
#define NBIN   8192
#define CAP    512
#define ABLK   256
#define BPI    8              // decode blocks per image
#define CPB    392            // cells per decode block (8*392 = 3136)

// ---------------- Kernel A: decode all boxes -> 64-bit keys in ws ----------------
// key = (score_bits << 18) | ((8191-idx) << 5) | cls   (score desc, idx asc, cls asc)
__global__ __launch_bounds__(ABLK) void decode_kernel(const float* __restrict__ in,
                                                      uint64_t* __restrict__ keys) {
#pragma clang fp contract(off)
    const int blk = blockIdx.x;
    const int img = blk >> 3;
    const int sub = blk & 7;
    const float* im = in + (size_t)img * DIM;
    uint64_t* kout = keys + (size_t)img * NBOXES;
    const int base = sub * CPB;
    #pragma unroll
    for (int i = 0; i < 2; i++) {
        int t = threadIdx.x + ABLK * i;
        if (t >= CPB) break;
        int cell = base + t;
        const float4* pv = (const float4*)(im + cell * NC);
        float p[NC];
        #pragma unroll
        for (int q = 0; q < 5; q++) {
            float4 v = pv[q];
            p[4*q+0] = v.x; p[4*q+1] = v.y; p[4*q+2] = v.z; p[4*q+3] = v.w;
        }
        float2 cf = *(const float2*)(im + BD1 + cell * 2);
        uint64_t kk[2];
        #pragma unroll
        for (int bb = 0; bb < 2; bb++) {
            float conf = bb ? cf.y : cf.x;
            float best = conf * p[0];   // rn product; first-occurrence argmax
            int   cls  = 0;
            #pragma unroll
            for (int c = 1; c < NC; c++) {
                float v = conf * p[c];
                if (v > best) { best = v; cls = c; }
            }
            uint32_t sb = (best >= 0.1f) ? __float_as_uint(best) : 0u;
            int idx = cell * 2 + bb;
            kk[bb] = ((uint64_t)sb << 18) | ((uint64_t)(8191 - idx) << 5) | (uint64_t)cls;
        }
        ulonglong2 st; st.x = kk[0]; st.y = kk[1];
        *(ulonglong2*)(kout + 2 * cell) = st;   // 16 B/thread, fully coalesced
    }
}

// ---------------- Kernel B: per-image select + sort + NMS + emit ----------------
__global__ __launch_bounds__(1024) void nms_kernel(const float* __restrict__ in,
                                                   const uint64_t* __restrict__ keys,
                                                   float* __restrict__ out) {
#pragma clang fp contract(off)
    const int b    = blockIdx.x;
    const int tid  = threadIdx.x;
    const int lane = tid & 63;
    const int wv   = tid >> 6;
    const float* img = in + (size_t)b * DIM;
    const uint64_t* kin = keys + (size_t)b * NBOXES;

    __shared__ uint32_t hist[NBIN];          // 32 KB
    __shared__ uint32_t wsum[16];
    __shared__ int      bstar_s;
    __shared__ int      nsel;
    __shared__ uint64_t skey[CAP];
    __shared__ uint64_t ssort[CAND];
    __shared__ float cymin[CAND], cxmin[CAND], cymax[CAND], cxmax[CAND];
    __shared__ float carea[CAND], cscore[CAND], ccls[CAND];
    __shared__ int   klist[MAXOUT];
    __shared__ float rowbuf[MAXOUT * 6];

    ((uint4*)hist)[tid]        = uint4{0,0,0,0};
    ((uint4*)hist)[tid + 1024] = uint4{0,0,0,0};
    if (tid == 0) nsel = 0;
    if (tid < MAXOUT) klist[tid] = -1;

    // coalesced key load: 7 passes of 8 B/lane
    uint64_t key[7];
    bool     vld[7];
    #pragma unroll
    for (int i = 0; i < 7; i++) {
        int j = tid + 1024 * i;
        vld[i] = (j < NBOXES);
        key[i] = vld[i] ? kin[j] : 0;
    }
    __syncthreads();   // B1: hist zeroed

    // single histogram pass (bin = score_bits >> 17)
    #pragma unroll
    for (int i = 0; i < 7; i++) {
        uint32_t sb = (uint32_t)(key[i] >> 18);
        if (vld[i] && sb != 0u) atomicAdd(&hist[sb >> 17], 1u);
        unsigned long long zm = __ballot(vld[i] && sb == 0u);
        if (lane == 0 && zm) atomicAdd(&hist[0], (uint32_t)__popcll(zm));
    }
    __syncthreads();   // B2

    // block suffix-scan over 8192 bins -> threshold bin b*
    uint4 h0 = ((const uint4*)hist)[2*tid];
    uint4 h1 = ((const uint4*)hist)[2*tid+1];
    uint32_t hsum = h0.x+h0.y+h0.z+h0.w + h1.x+h1.y+h1.z+h1.w;
    uint32_t v = hsum;
    #pragma unroll
    for (int off = 1; off < 64; off <<= 1) {
        uint32_t u = __shfl_down(v, off);
        if (lane + off < 64) v += u;
    }
    if (lane == 0) wsum[wv] = v;
    __syncthreads();   // B3
    uint32_t add = 0;
    for (int w = wv + 1; w < 16; w++) add += wsum[w];
    uint32_t Sm    = v + add;       // elems in bins >= 8*tid
    uint32_t above = Sm - hsum;     // elems in bins >= 8*(tid+1)
    if (above < CAND && CAND <= Sm) {   // exactly one thread
        uint32_t hh[8] = {h1.w, h1.z, h1.y, h1.x, h0.w, h0.z, h0.y, h0.x};
        uint32_t g = above;
        int bsel = 8 * tid;
        #pragma unroll
        for (int j = 0; j < 8; j++) {
            if (g + hh[j] >= CAND) { bsel = 8 * tid + (7 - j); break; }
            g += hh[j];
        }
        bstar_s = bsel;
    }
    __syncthreads();   // B4
    const uint32_t bstar = (uint32_t)bstar_s;

    // compact superset (bin >= b*), wave-aggregated atomics
    #pragma unroll
    for (int i = 0; i < 7; i++) {
        bool pred = vld[i] && ((uint32_t)(key[i] >> 35) >= bstar);
        unsigned long long mask = __ballot(pred);
        if (mask) {
            int leader = __ffsll(mask) - 1;
            int base = 0;
            if (lane == leader) base = atomicAdd(&nsel, (int)__popcll(mask));
            base = __shfl(base, leader);
            if (pred) {
                int pos = base + (int)__popcll(mask & ((1ull << lane) - 1ull));
                if (pos < CAP) skey[pos] = key[i];
            }
        }
    }
    __syncthreads();   // B5

    // rank-sort top-256 of the M-superset (keys unique)
    const int M = (nsel < CAP) ? nsel : CAP;
    if (tid < M) {
        uint64_t my = skey[tid];
        int r = 0;
        #pragma unroll 4
        for (int j = 0; j < M; j++) r += (skey[j] > my);
        if (r < CAND) ssort[r] = my;
    }
    __syncthreads();   // B6

    // decode the 256 candidate boxes
    if (tid < CAND) {
        uint64_t k = ssort[tid];
        int idx      = 8191 - (int)((k >> 5) & 0x1FFF);
        int cls      = (int)(k & 31u);
        uint32_t sb  = (uint32_t)(k >> 18);
        int cell = idx >> 1, bb = idx & 1;
        int i = cell / S, j = cell - i * S;   // i = row (y), j = col (x)
        float4 co = *(const float4*)(img + BD2 + cell * 8 + bb * 4);
        float x  = (co.x + (float)j) / 56.0f;
        float y  = (co.y + (float)i) / 56.0f;
        float wx = co.z * co.z;
        float wy = co.w * co.w;
        float hx = wx * 0.5f, hy = wy * 0.5f;
        float xmin = x - hx, ymin = y - hy, xmax = x + hx, ymax = y + hy;
        cymin[tid] = ymin; cxmin[tid] = xmin; cymax[tid] = ymax; cxmax[tid] = xmax;
        carea[tid] = fmaxf(ymax - ymin, 0.0f) * fmaxf(xmax - xmin, 0.0f);
        cscore[tid] = __uint_as_float(sb);
        ccls[tid]   = (float)cls;
    }
    __syncthreads();   // B7

    // single-wave greedy NMS (lane owns 4 consecutive candidates)
    if (wv == 0) {
        float bym[4], bxm[4], byM[4], bxM[4], bar[4];
        #pragma unroll
        for (int s = 0; s < 4; s++) {
            int c = 4 * lane + s;
            bym[s] = cymin[c]; bxm[s] = cxmin[c];
            byM[s] = cymax[c]; bxM[s] = cxmax[c]; bar[s] = carea[c];
        }
        unsigned vmask = 0xFu;
        for (int it = 0; it < MAXOUT; it++) {
            unsigned long long mk = __ballot(vmask != 0u);
            if (!mk) break;
            int l0 = __ffsll(mk) - 1;
            int vb = __shfl((int)vmask, l0);
            int p  = 4 * l0 + (__ffs(vb) - 1);
            if (lane == 0) klist[it] = p;
            float pym = cymin[p], pxm = cxmin[p];
            float pyM = cymax[p], pxM = cxmax[p], par = carea[p];
            #pragma unroll
            for (int s = 0; s < 4; s++) {
                int c = 4 * lane + s;
                float iy = fmaxf(0.0f, fminf(pyM, byM[s]) - fmaxf(pym, bym[s]));
                float ix = fmaxf(0.0f, fminf(pxM, bxM[s]) - fmaxf(pxm, bxm[s]));
                float inter = iy * ix;
                float uni   = par + bar[s] - inter;
                float iou   = (uni > 0.0f) ? (inter / uni) : 0.0f;  // exact IEEE div
                if (c == p || !(iou <= 0.4f)) vmask &= ~(1u << s);
            }
        }
    }
    __syncthreads();   // B8

    // emit 30x6 rows
    if (tid < MAXOUT) {
        int p = klist[tid];
        float* r = &rowbuf[tid * 6];
        if (p >= 0) {
            r[0] = cymin[p]; r[1] = cxmin[p]; r[2] = cymax[p];
            r[3] = cxmax[p]; r[4] = cscore[p]; r[5] = ccls[p];
        } else {
            r[0] = r[1] = r[2] = r[3] = r[4] = r[5] = 0.0f;
        }
    }
    __syncthreads();   // B9
    float* ob = out + (size_t)b * (MAXOUT * 6);
    if (tid < MAXOUT * 6) ob[tid] = rowbuf[tid];
}

extern "C" void kernel_launch(void* const* d_in, const int* in_sizes, int n_in,
                              void* d_out, int out_size, void* d_ws, size_t ws_size,
                              hipStream_t stream) {
    const float* in  = (const float*)d_in[0];
    float*       out = (float*)d_out;
    uint64_t*    keys = (uint64_t*)d_ws;     // 256*6272*8 B = 12.85 MB
    const int B = in_sizes[0] / DIM;         // 256
    decode_kernel<<<dim3(B * BPI), dim3(ABLK), 0, stream>>>(in, keys);
    nms_kernel<<<dim3(B), dim3(1024), 0, stream>>>(in, keys, out);
}